// Round 5
// baseline (4760.787 us; speedup 1.0000x reference)
//
#include <hip/hip_runtime.h>
#include <stdint.h>

#define BB 8
#define CCH 64
#define NPB 4096
#define KK 16
#define NPTS (BB*NPB)   // 32768
#define SPLITS 8

typedef float vf16 __attribute__((ext_vector_type(16)));

// ---------------- K1: transpose x (B,C,N) -> xb (B,N,C) ----------------
__global__ void k_transpose(const float* __restrict__ x, float* __restrict__ xb) {
    __shared__ float tile[64][65];
    int b  = blockIdx.y;
    int n0 = blockIdx.x * 64;
    int tx = threadIdx.x, ty = threadIdx.y;   // 64 x 8
    const float* xp = x + (size_t)b * CCH * NPB;
#pragma unroll
    for (int r = 0; r < 8; ++r) {
        int c = ty + r * 8;
        tile[c][tx] = xp[(size_t)c * NPB + n0 + tx];
    }
    __syncthreads();
    float* xbp = xb + ((size_t)b * NPB + n0) * CCH;
#pragma unroll
    for (int r = 0; r < 8; ++r) {
        int nn = ty + r * 8;
        xbp[(size_t)nn * CCH + tx] = tile[tx][nn];
    }
}

// ---------------- K1b: per-point sum of squares ----------------
__global__ void k_sq(const float* __restrict__ xb, float* __restrict__ sq) {
    int p = blockIdx.x * 256 + threadIdx.x;
    const float4* r = (const float4*)(xb + (size_t)p * CCH);
    float s = 0.0f;
#pragma unroll
    for (int i = 0; i < 16; ++i) {
        float4 v = r[i];
        s += v.x * v.x + v.y * v.y + v.z * v.z + v.w * v.w;
    }
    sq[p] = s;
}

// ---------------- K2: distances + per-(row,colsplit) top-16 ----------------
// R1 body mechanics (per-lane bases, vf16 dual-col loads, d[64], u64 list)
// with: 256-thread blocks (R4 showed 512-blocks never co-schedule 2/CU) and
// a 4-way split min-scan (dep depth ~130cy instead of ~500cy serial).
// key = (monotonic_bits(sq[col] - 2*dot) << 32) | col -> lex (d asc, idx asc)
__global__ __launch_bounds__(256, 4) void k_knn(const float* __restrict__ xb,
                                                const float* __restrict__ sq,
                                                unsigned long long* __restrict__ cand) {
    int tid  = threadIdx.x;
    int row  = blockIdx.y * 256 + tid;          // global point (per-lane)
    int b    = row >> 12;                       // per-lane on purpose
    int split = blockIdx.x;
    const float* xbB = xb + ((size_t)(b) << 12) * CCH;
    const float* sqB = sq + ((size_t)(b) << 12);

    // my row's features -> registers
    float rr[CCH];
    {
        const float4* rp = (const float4*)(xbB + (size_t)(row & 4095) * CCH);
#pragma unroll
        for (int i = 0; i < 16; ++i) {
            float4 v = rp[i];
            rr[4*i] = v.x; rr[4*i+1] = v.y; rr[4*i+2] = v.z; rr[4*i+3] = v.w;
        }
    }

    unsigned long long list[16];
#pragma unroll
    for (int s = 0; s < 16; ++s) list[s] = ~0ULL;

    int colBase = split * (NPB / SPLITS);       // 512 cols per split
    for (int t = 0; t < (NPB / SPLITS) / 64; ++t) {   // 8 tiles of 64 cols
        int c0 = colBase + t * 64;
        float d[64];
        // ---- compute d[cc] = sq[col] - 2*dot(row,col) ----
#pragma unroll
        for (int cc = 0; cc < 64; cc += 2) {
            float a0 = 0.f, a1 = 0.f;
            const float* col0 = xbB + (size_t)(c0 + cc) * CCH;
            const float* col1 = xbB + (size_t)(c0 + cc + 1) * CCH;
#pragma unroll
            for (int q = 0; q < 4; ++q) {
                vf16 v0 = *(const vf16*)(col0 + q * 16);
                vf16 v1 = *(const vf16*)(col1 + q * 16);
#pragma unroll
                for (int e = 0; e < 16; ++e) {
                    a0 = fmaf(v0[e], rr[q * 16 + e], a0);
                    a1 = fmaf(v1[e], rr[q * 16 + e], a1);
                }
            }
            d[cc]     = fmaf(-2.f, a0, sqB[c0 + cc]);
            d[cc + 1] = fmaf(-2.f, a1, sqB[c0 + cc + 1]);
        }
        // ---- selection rounds: extract tile-min (4-way chains), insert ----
        while (true) {
            float m0 = d[0];  int x0 = 0;
            float m1 = d[16]; int x1 = 16;
            float m2 = d[32]; int x2 = 32;
            float m3 = d[48]; int x3 = 48;
#pragma unroll
            for (int s = 1; s < 16; ++s) {
                bool l0 = d[s]      < m0; m0 = l0 ? d[s]      : m0; x0 = l0 ? s      : x0;
                bool l1 = d[16 + s] < m1; m1 = l1 ? d[16 + s] : m1; x1 = l1 ? 16 + s : x1;
                bool l2 = d[32 + s] < m2; m2 = l2 ? d[32 + s] : m2; x2 = l2 ? 32 + s : x2;
                bool l3 = d[48 + s] < m3; m3 = l3 ? d[48 + s] : m3; x3 = l3 ? 48 + s : x3;
            }
            // merge: strict < from higher-index side keeps lowest col on ties
            bool t1 = m1 < m0; float ma = t1 ? m1 : m0; int xa = t1 ? x1 : x0;
            bool t2 = m3 < m2; float mb = t2 ? m3 : m2; int xb2 = t2 ? x3 : x2;
            bool t3 = mb < ma; float mv = t3 ? mb : ma; int ms = t3 ? xb2 : xa;

            unsigned int fb = __float_as_uint(mv);
            fb ^= (fb >> 31) ? 0xFFFFFFFFu : 0x80000000u;   // monotonic transform
            unsigned long long key =
                ((unsigned long long)fb << 32) | (unsigned int)(c0 + ms);
            bool want = key < list[15];
            if (!__any(want)) break;
            if (want) {
                bool bs[16];
#pragma unroll
                for (int s = 0; s < 16; ++s) bs[s] = key < list[s];
#pragma unroll
                for (int s = 15; s >= 1; --s)
                    list[s] = bs[s] ? (bs[s - 1] ? list[s - 1] : key) : list[s];
                list[0] = bs[0] ? key : list[0];
#pragma unroll
                for (int s = 0; s < 64; ++s)
                    if (s == ms) d[s] = __builtin_inff();
            }
        }
    }
    unsigned long long* cp = cand + (((size_t)row * SPLITS) + split) * 16;
#pragma unroll
    for (int s = 0; s < 16; ++s) cp[s] = list[s];
}

// ---------------- K3: merge SPLITS sorted 16-lists -> final idx[16] ----------------
__global__ void k_merge(const unsigned long long* __restrict__ cand,
                        int* __restrict__ idxo) {
    int row = blockIdx.x * 256 + threadIdx.x;
    const unsigned long long* cp = cand + (size_t)row * (SPLITS * 16);
    int p[SPLITS];
#pragma unroll
    for (int s = 0; s < SPLITS; ++s) p[s] = 0;
    for (int k = 0; k < 16; ++k) {
        unsigned long long m = ~0ULL; int w = 0;
#pragma unroll
        for (int s = 0; s < SPLITS; ++s) {
            unsigned long long v = cp[s * 16 + p[s]];
            if (v < m) { m = v; w = s; }       // strict: earlier split wins ties
        }
#pragma unroll
        for (int s = 0; s < SPLITS; ++s) p[s] += (s == w) ? 1 : 0;
        idxo[(size_t)row * 16 + k] = (int)(m & 0xFFFFFFFFu);
    }
}

// ---------------- K4: fused edge-MLP + max over K (proven body) ----------------
__global__ __launch_bounds__(256, 2) void k_mlp(const float* __restrict__ xb,
                                                const int* __restrict__ idx,
                                                const float* __restrict__ W1,
                                                const float* __restrict__ b1,
                                                const float* __restrict__ W2,
                                                const float* __restrict__ b2,
                                                float* __restrict__ out) {
    int lane = threadIdx.x & 63;
    int wave = (blockIdx.x * 256 + threadIdx.x) >> 6;   // 0..2047
    int o = lane;
    float wa[64], wb[64], w2r[64];
#pragma unroll
    for (int c = 0; c < 64; ++c) {
        float w1a = W1[c * 64 + o];
        float w1b = W1[(64 + c) * 64 + o];
        wa[c] = w1a - w1b;
        wb[c] = w1b;
        w2r[c] = W2[c * 64 + o];
    }
    float bb1 = b1[o], bb2 = b2[o];
    int p0 = wave * 16;
    for (int pi = 0; pi < 16; ++pi) {
        int p = p0 + pi;
        int b = p >> 12;
        int n = p & 4095;
        const float* xbB = xb + ((size_t)b << 12) * CCH;
        const float* xi = xbB + (size_t)n * CCH;
        float pre = bb1;
#pragma unroll
        for (int c4 = 0; c4 < 16; ++c4) {
            float4 v = *(const float4*)(xi + c4 * 4);
            pre = fmaf(v.x, wa[c4 * 4 + 0], pre);
            pre = fmaf(v.y, wa[c4 * 4 + 1], pre);
            pre = fmaf(v.z, wa[c4 * 4 + 2], pre);
            pre = fmaf(v.w, wa[c4 * 4 + 3], pre);
        }
        const int* ip = idx + (size_t)p * 16;
        float mx = 0.f;
        for (int k = 0; k < 16; ++k) {
            int j = ip[k];
            const float* xj = xbB + (size_t)j * CCH;
            float h = pre;
#pragma unroll
            for (int c4 = 0; c4 < 16; ++c4) {
                float4 v = *(const float4*)(xj + c4 * 4);
                h = fmaf(v.x, wb[c4 * 4 + 0], h);
                h = fmaf(v.y, wb[c4 * 4 + 1], h);
                h = fmaf(v.z, wb[c4 * 4 + 2], h);
                h = fmaf(v.w, wb[c4 * 4 + 3], h);
            }
            float h1 = fmaxf(h, 0.f);
            float a0 = bb2, a1 = 0.f, a2 = 0.f, a3 = 0.f;
#pragma unroll
            for (int j4 = 0; j4 < 16; ++j4) {
                float h0  = __int_as_float(__builtin_amdgcn_readlane(__float_as_int(h1), 4*j4+0));
                float hh1 = __int_as_float(__builtin_amdgcn_readlane(__float_as_int(h1), 4*j4+1));
                float h2  = __int_as_float(__builtin_amdgcn_readlane(__float_as_int(h1), 4*j4+2));
                float h3  = __int_as_float(__builtin_amdgcn_readlane(__float_as_int(h1), 4*j4+3));
                a0 = fmaf(h0,  w2r[4*j4+0], a0);
                a1 = fmaf(hh1, w2r[4*j4+1], a1);
                a2 = fmaf(h2,  w2r[4*j4+2], a2);
                a3 = fmaf(h3,  w2r[4*j4+3], a3);
            }
            float acc = (a0 + a1) + (a2 + a3);
            float h2o = fmaxf(acc, 0.f);
            mx = fmaxf(mx, h2o);
        }
        out[((size_t)b * 64 + o) * NPB + n] = mx;
    }
}

extern "C" void kernel_launch(void* const* d_in, const int* in_sizes, int n_in,
                              void* d_out, int out_size, void* d_ws, size_t ws_size,
                              hipStream_t stream) {
    const float* x  = (const float*)d_in[0];
    const float* W1 = (const float*)d_in[1];
    const float* b1 = (const float*)d_in[2];
    const float* W2 = (const float*)d_in[3];
    const float* b2 = (const float*)d_in[4];
    float* out = (float*)d_out;

    char* ws = (char*)d_ws;
    float* xb = (float*)ws;                                       // 8 MB
    float* sq = (float*)(ws + (size_t)8 * 1024 * 1024);           // 128 KB
    unsigned long long* cand =
        (unsigned long long*)(ws + (size_t)9 * 1024 * 1024);      // 32 MB
    int* idxb = (int*)(ws + (size_t)9 * 1024 * 1024
                          + (size_t)NPTS * SPLITS * 16 * 8);      // 2 MB

    hipLaunchKernelGGL(k_transpose, dim3(NPB / 64, BB), dim3(64, 8), 0, stream, x, xb);
    hipLaunchKernelGGL(k_sq, dim3(NPTS / 256), dim3(256), 0, stream, xb, sq);
    hipLaunchKernelGGL(k_knn, dim3(SPLITS, NPTS / 256), dim3(256), 0, stream, xb, sq, cand);
    hipLaunchKernelGGL(k_merge, dim3(NPTS / 256), dim3(256), 0, stream, cand, idxb);
    hipLaunchKernelGGL(k_mlp, dim3(512), dim3(256), 0, stream, xb, idxb, W1, b1, W2, b2, out);
}

// Round 6
// 1407.263 us; speedup vs baseline: 3.3830x; 3.3830x over previous
//
#include <hip/hip_runtime.h>
#include <stdint.h>

#define BB 8
#define CCH 64
#define NPB 4096
#define KK 16
#define NPTS (BB*NPB)   // 32768
#define SPLITS 8

typedef float vf16 __attribute__((ext_vector_type(16)));
typedef unsigned long long u64;

// ---------------- K1: transpose x (B,C,N) -> xb (B,N,C) ----------------
__global__ void k_transpose(const float* __restrict__ x, float* __restrict__ xb) {
    __shared__ float tile[64][65];
    int b  = blockIdx.y;
    int n0 = blockIdx.x * 64;
    int tx = threadIdx.x, ty = threadIdx.y;   // 64 x 8
    const float* xp = x + (size_t)b * CCH * NPB;
#pragma unroll
    for (int r = 0; r < 8; ++r) {
        int c = ty + r * 8;
        tile[c][tx] = xp[(size_t)c * NPB + n0 + tx];
    }
    __syncthreads();
    float* xbp = xb + ((size_t)b * NPB + n0) * CCH;
#pragma unroll
    for (int r = 0; r < 8; ++r) {
        int nn = ty + r * 8;
        xbp[(size_t)nn * CCH + tx] = tile[tx][nn];
    }
}

// ---------------- K1b: per-point sum of squares ----------------
__global__ void k_sq(const float* __restrict__ xb, float* __restrict__ sq) {
    int p = blockIdx.x * 256 + threadIdx.x;
    const float4* r = (const float4*)(xb + (size_t)p * CCH);
    float s = 0.0f;
#pragma unroll
    for (int i = 0; i < 16; ++i) {
        float4 v = r[i];
        s += v.x * v.x + v.y * v.y + v.z * v.z + v.w * v.w;
    }
    sq[p] = s;
}

// ---------------- K2: distances + per-(row,colsplit) top-16 ----------------
// (512,2) bounds: proven clean codegen (VGPR=128/SGPR=32 in R1/R4; 256-reg
// budget). Selection rewritten as branchless bitonic sort16 + merge16 per
// 16-col subtile — no while-rounds, no serial 63-step min-scan, no dynamic
// register indexing. Keys u64 (monotonic-f32 << 32 | col): exact (d asc,
// idx asc) ordering, identical semantics to R1/R4's passing lists.
__global__ __launch_bounds__(512, 2) void k_knn(const float* __restrict__ xb,
                                                const float* __restrict__ sq,
                                                u64* __restrict__ cand) {
    int tid  = threadIdx.x;
    int row  = blockIdx.y * 512 + tid;          // global point (per-lane)
    int b    = row >> 12;                       // per-lane on purpose
    int split = blockIdx.x;
    const float* xbB = xb + ((size_t)(b) << 12) * CCH;
    const float* sqB = sq + ((size_t)(b) << 12);

    // my row's features -> registers
    float rr[CCH];
    {
        const float4* rp = (const float4*)(xbB + (size_t)(row & 4095) * CCH);
#pragma unroll
        for (int i = 0; i < 16; ++i) {
            float4 v = rp[i];
            rr[4*i] = v.x; rr[4*i+1] = v.y; rr[4*i+2] = v.z; rr[4*i+3] = v.w;
        }
    }

    u64 list[16];
#pragma unroll
    for (int s = 0; s < 16; ++s) list[s] = ~0ULL;

    int colBase = split * (NPB / SPLITS);       // 512 cols per split
    for (int t = 0; t < (NPB / SPLITS) / 16; ++t) {   // 32 subtiles of 16 cols
        int c0 = colBase + t * 16;
        u64 key[16];
        // ---- distances: EXACT R1 accumulation order (bit-identical d) ----
#pragma unroll
        for (int cc = 0; cc < 16; cc += 2) {
            float a0 = 0.f, a1 = 0.f;
            const float* col0 = xbB + (size_t)(c0 + cc) * CCH;
            const float* col1 = xbB + (size_t)(c0 + cc + 1) * CCH;
#pragma unroll
            for (int q = 0; q < 4; ++q) {
                vf16 v0 = *(const vf16*)(col0 + q * 16);
                vf16 v1 = *(const vf16*)(col1 + q * 16);
#pragma unroll
                for (int e = 0; e < 16; ++e) {
                    a0 = fmaf(v0[e], rr[q * 16 + e], a0);
                    a1 = fmaf(v1[e], rr[q * 16 + e], a1);
                }
            }
            float d0 = fmaf(-2.f, a0, sqB[c0 + cc]);
            float d1 = fmaf(-2.f, a1, sqB[c0 + cc + 1]);
            unsigned int f0 = __float_as_uint(d0);
            unsigned int f1 = __float_as_uint(d1);
            f0 ^= (f0 >> 31) ? 0xFFFFFFFFu : 0x80000000u;   // monotonic
            f1 ^= (f1 >> 31) ? 0xFFFFFFFFu : 0x80000000u;
            key[cc]     = ((u64)f0 << 32) | (unsigned int)(c0 + cc);
            key[cc + 1] = ((u64)f1 << 32) | (unsigned int)(c0 + cc + 1);
        }
        // ---- bitonic sort16 ascending (static indices, branchless) ----
#pragma unroll
        for (int kk = 2; kk <= 16; kk <<= 1) {
#pragma unroll
            for (int j = kk >> 1; j > 0; j >>= 1) {
#pragma unroll
                for (int i = 0; i < 16; ++i) {
                    int l = i ^ j;
                    if (l > i) {
                        bool up = ((i & kk) == 0);
                        u64 a = key[i], c = key[l];
                        bool cond = up ? (c < a) : (a < c);
                        key[i] = cond ? c : a;
                        key[l] = cond ? a : c;
                    }
                }
            }
        }
        // ---- merge: keep 16 smallest of (list[16] asc, key[16] asc) ----
        u64 m[16];
#pragma unroll
        for (int i = 0; i < 16; ++i) {
            u64 a = list[i], c = key[15 - i];
            m[i] = (c < a) ? c : a;            // bitonic result
        }
#pragma unroll
        for (int j = 8; j > 0; j >>= 1) {
#pragma unroll
            for (int i = 0; i < 16; ++i) {
                if ((i & j) == 0) {
                    u64 a = m[i], c = m[i + j];
                    bool cond = c < a;
                    m[i]     = cond ? c : a;
                    m[i + j] = cond ? a : c;
                }
            }
        }
#pragma unroll
        for (int i = 0; i < 16; ++i) list[i] = m[i];
    }
    u64* cp = cand + (((size_t)row * SPLITS) + split) * 16;
#pragma unroll
    for (int s = 0; s < 16; ++s) cp[s] = list[s];
}

// ---------------- K3: merge SPLITS sorted 16-lists -> final idx[16] ----------------
__global__ void k_merge(const u64* __restrict__ cand,
                        int* __restrict__ idxo) {
    int row = blockIdx.x * 256 + threadIdx.x;
    const u64* cp = cand + (size_t)row * (SPLITS * 16);
    int p[SPLITS];
#pragma unroll
    for (int s = 0; s < SPLITS; ++s) p[s] = 0;
    for (int k = 0; k < 16; ++k) {
        u64 m = ~0ULL; int w = 0;
#pragma unroll
        for (int s = 0; s < SPLITS; ++s) {
            u64 v = cp[s * 16 + p[s]];
            if (v < m) { m = v; w = s; }       // strict: earlier split wins ties
        }
#pragma unroll
        for (int s = 0; s < SPLITS; ++s) p[s] += (s == w) ? 1 : 0;
        idxo[(size_t)row * 16 + k] = (int)(m & 0xFFFFFFFFu);
    }
}

// ---------------- K4: fused edge-MLP + max over K (proven body) ----------------
__global__ __launch_bounds__(256, 2) void k_mlp(const float* __restrict__ xb,
                                                const int* __restrict__ idx,
                                                const float* __restrict__ W1,
                                                const float* __restrict__ b1,
                                                const float* __restrict__ W2,
                                                const float* __restrict__ b2,
                                                float* __restrict__ out) {
    int lane = threadIdx.x & 63;
    int wave = (blockIdx.x * 256 + threadIdx.x) >> 6;   // 0..2047
    int o = lane;
    float wa[64], wb[64], w2r[64];
#pragma unroll
    for (int c = 0; c < 64; ++c) {
        float w1a = W1[c * 64 + o];
        float w1b = W1[(64 + c) * 64 + o];
        wa[c] = w1a - w1b;
        wb[c] = w1b;
        w2r[c] = W2[c * 64 + o];
    }
    float bb1 = b1[o], bb2 = b2[o];
    int p0 = wave * 16;
    for (int pi = 0; pi < 16; ++pi) {
        int p = p0 + pi;
        int b = p >> 12;
        int n = p & 4095;
        const float* xbB = xb + ((size_t)b << 12) * CCH;
        const float* xi = xbB + (size_t)n * CCH;
        float pre = bb1;
#pragma unroll
        for (int c4 = 0; c4 < 16; ++c4) {
            float4 v = *(const float4*)(xi + c4 * 4);
            pre = fmaf(v.x, wa[c4 * 4 + 0], pre);
            pre = fmaf(v.y, wa[c4 * 4 + 1], pre);
            pre = fmaf(v.z, wa[c4 * 4 + 2], pre);
            pre = fmaf(v.w, wa[c4 * 4 + 3], pre);
        }
        const int* ip = idx + (size_t)p * 16;
        float mx = 0.f;
        for (int k = 0; k < 16; ++k) {
            int j = ip[k];
            const float* xj = xbB + (size_t)j * CCH;
            float h = pre;
#pragma unroll
            for (int c4 = 0; c4 < 16; ++c4) {
                float4 v = *(const float4*)(xj + c4 * 4);
                h = fmaf(v.x, wb[c4 * 4 + 0], h);
                h = fmaf(v.y, wb[c4 * 4 + 1], h);
                h = fmaf(v.z, wb[c4 * 4 + 2], h);
                h = fmaf(v.w, wb[c4 * 4 + 3], h);
            }
            float h1 = fmaxf(h, 0.f);
            float a0 = bb2, a1 = 0.f, a2 = 0.f, a3 = 0.f;
#pragma unroll
            for (int j4 = 0; j4 < 16; ++j4) {
                float h0  = __int_as_float(__builtin_amdgcn_readlane(__float_as_int(h1), 4*j4+0));
                float hh1 = __int_as_float(__builtin_amdgcn_readlane(__float_as_int(h1), 4*j4+1));
                float h2  = __int_as_float(__builtin_amdgcn_readlane(__float_as_int(h1), 4*j4+2));
                float h3  = __int_as_float(__builtin_amdgcn_readlane(__float_as_int(h1), 4*j4+3));
                a0 = fmaf(h0,  w2r[4*j4+0], a0);
                a1 = fmaf(hh1, w2r[4*j4+1], a1);
                a2 = fmaf(h2,  w2r[4*j4+2], a2);
                a3 = fmaf(h3,  w2r[4*j4+3], a3);
            }
            float acc = (a0 + a1) + (a2 + a3);
            float h2o = fmaxf(acc, 0.f);
            mx = fmaxf(mx, h2o);
        }
        out[((size_t)b * 64 + o) * NPB + n] = mx;
    }
}

extern "C" void kernel_launch(void* const* d_in, const int* in_sizes, int n_in,
                              void* d_out, int out_size, void* d_ws, size_t ws_size,
                              hipStream_t stream) {
    const float* x  = (const float*)d_in[0];
    const float* W1 = (const float*)d_in[1];
    const float* b1 = (const float*)d_in[2];
    const float* W2 = (const float*)d_in[3];
    const float* b2 = (const float*)d_in[4];
    float* out = (float*)d_out;

    char* ws = (char*)d_ws;
    float* xb = (float*)ws;                                       // 8 MB
    float* sq = (float*)(ws + (size_t)8 * 1024 * 1024);           // 128 KB
    u64* cand = (u64*)(ws + (size_t)9 * 1024 * 1024);             // 32 MB
    int* idxb = (int*)(ws + (size_t)9 * 1024 * 1024
                          + (size_t)NPTS * SPLITS * 16 * 8);      // 2 MB

    hipLaunchKernelGGL(k_transpose, dim3(NPB / 64, BB), dim3(64, 8), 0, stream, x, xb);
    hipLaunchKernelGGL(k_sq, dim3(NPTS / 256), dim3(256), 0, stream, xb, sq);
    hipLaunchKernelGGL(k_knn, dim3(SPLITS, NPTS / 512), dim3(512), 0, stream, xb, sq, cand);
    hipLaunchKernelGGL(k_merge, dim3(NPTS / 256), dim3(256), 0, stream, cand, idxb);
    hipLaunchKernelGGL(k_mlp, dim3(512), dim3(256), 0, stream, xb, idxb, W1, b1, W2, b2, out);
}